// Round 15
// baseline (77.191 us; speedup 1.0000x reference)
//
#include <hip/hip_runtime.h>
#include <math.h>

// R15 = R14 with the compile fix (D-fragment names dA/dB/dC no longer shadow
// the geometry distances d1/d2/d3). Per-wave MFMA GEMM for the scalar path:
// D[64x16] = A[64x128] x B[128x16] -> 16x v_mfma_f32_16x16x32_f16.
// k-labeling (consistent for A and B, so any HW k-permutation cancels):
//   k<100: p12[k/5]*s3[k%5] | 100..104: dot12*s3[k-100] | 105..124: p12[k-105]
//   k==125: dot12 | 126,127: 0
// B cols: 0..8 = W12/WV stack (accs), col 9 = WS/cS stack (S), 10..15 = 0.
// C/D layout (m89-verified): col = lane&15, row = (lane>>4)*4 + reg.
// A: row = lane&15, k-group = lane>>4 (8 f16). B: col = lane&15, same k-group.
// Staging: per-wave private LDS slice (64 rows x 72 B), 4 write->read rounds
// ordered by __syncthreads (no early returns; OOB lanes clamp loads, skip
// stores). D redistributed via the same slice (64 x 64 B).

typedef _Float16 h2 __attribute__((ext_vector_type(2)));
typedef _Float16 h8 __attribute__((ext_vector_type(8)));
typedef float    f4v __attribute__((ext_vector_type(4)));
typedef float    f2v __attribute__((ext_vector_type(2)));

#define WS_BF   0     // [4 slices][64 lanes][4 dwords] B fragments = 1024
#define WS_SVV  1024  // [5][5] f32 *i10
#define WS_VSV  1049  // [4][5] f32 *i10
#define WS_VVV1 1069  // [5]    f32 *i10*i2
#define WS_VSV2 1074  // [5][5] f32 *i50
#define WS_VVV2 1099  // [5]    f32 *i2*i50
#define WS_VVO2 1104  // [5][9] f32 *i3*i105
#define WS_TOT  1149

__device__ float wf_entry(int k, int o,
                          const float* __restrict__ W1_sso,
                          const float* __restrict__ W1_vvo,
                          const float* __restrict__ W2_sso,
                          const float* __restrict__ W2_svv) {
    const float I3 = 0.57735026918962576f, I21 = 0.21821789023599239f;
    const float I105 = 0.09759000729485332f, I50 = 0.14142135623730950f;
    if (o < 9) {
        if (k < 100) {
            int ij = k / 5, j3 = k % 5;
            float acc = 0.f;
            for (int k2 = 0; k2 < 20; k2++)
                acc = fmaf(W1_sso[ij * 20 + k2], W2_sso[(k2 * 5 + j3) * 9 + o], acc);
            return acc * (I21 * I105);
        } else if (k < 105) {
            int j3 = k - 100;
            float acc = 0.f;
            for (int k2 = 0; k2 < 20; k2++)
                acc = fmaf(W1_vvo[k2], W2_sso[(k2 * 5 + j3) * 9 + o], acc);
            return acc * (I21 * I105 * I3);
        }
        return 0.f;
    } else if (o == 9) {
        if (k >= 105 && k < 125) {
            int ij = k - 105;
            float acc = 0.f;
            for (int k2 = 0; k2 < 20; k2++)
                acc = fmaf(W1_sso[ij * 20 + k2], W2_svv[k2], acc);
            return acc * (I21 * I50);
        } else if (k == 125) {
            float acc = 0.f;
            for (int k2 = 0; k2 < 20; k2++)
                acc = fmaf(W1_vvo[k2], W2_svv[k2], acc);
            return acc * (I21 * I50 * I3);
        }
        return 0.f;
    }
    return 0.f;
}

__global__ __launch_bounds__(256) void fds_precompose(
    const float* __restrict__ W1_sso, const float* __restrict__ W1_svv,
    const float* __restrict__ W1_vsv, const float* __restrict__ W1_vvo,
    const float* __restrict__ W1_vvv, const float* __restrict__ W2_sso,
    const float* __restrict__ W2_svv, const float* __restrict__ W2_vsv,
    const float* __restrict__ W2_vvo, const float* __restrict__ W2_vvv,
    float* __restrict__ ws)
{
    const float I2 = 0.70710678118654752f, I3 = 0.57735026918962576f;
    const float I10 = 0.31622776601683794f, I105 = 0.09759000729485332f;
    const float I50 = 0.14142135623730950f;
    int tid = threadIdx.x;
    // B fragments: dword idx -> slice s = idx>>8, lane = (idx>>2)&63, i = idx&3
    for (int idx = tid; idx < 1024; idx += 256) {
        int i = idx & 3, lane = (idx >> 2) & 63, s = idx >> 8;
        int col = lane & 15;
        int k0 = s * 32 + (lane >> 4) * 8 + i * 2;
        h2 p = { (_Float16)wf_entry(k0,     col, W1_sso, W1_vvo, W2_sso, W2_svv),
                 (_Float16)wf_entry(k0 + 1, col, W1_sso, W1_vvo, W2_sso, W2_svv) };
        ws[WS_BF + idx] = __builtin_bit_cast(float, p);
    }
    for (int idx = tid; idx < 25; idx += 256) ws[WS_SVV + idx] = W1_svv[idx] * I10;
    for (int idx = tid; idx < 20; idx += 256) ws[WS_VSV + idx] = W1_vsv[idx] * I10;
    for (int idx = tid; idx < 5; idx += 256)  ws[WS_VVV1 + idx] = W1_vvv[idx] * (I10 * I2);
    for (int idx = tid; idx < 25; idx += 256) ws[WS_VSV2 + idx] = W2_vsv[idx] * I50;
    for (int idx = tid; idx < 5; idx += 256)  ws[WS_VVV2 + idx] = W2_vvv[idx] * (I2 * I50);
    for (int idx = tid; idx < 45; idx += 256) ws[WS_VVO2 + idx] = W2_vvo[idx] * (I3 * I105);
}

// feature element for compile-time k (constant-folded in unrolled loops)
#define FEAT(K) ((K) < 100 ? p12f[(K) / 5] * s3f[(K) % 5] : \
                 (K) < 105 ? d12h * s3f[(K) - 100] :        \
                 (K) < 125 ? p12f[(K) - 105] :              \
                 (K) == 125 ? d12h : (_Float16)0.f)

__global__ __launch_bounds__(256) void fds_kernel(
    const float* __restrict__ lig, const float* __restrict__ rec,
    const float* __restrict__ BF, const float* __restrict__ SVV,
    const float* __restrict__ VSV, const float* __restrict__ VVV1,
    const float* __restrict__ VSV2, const float* __restrict__ VVV2,
    const float* __restrict__ VVO2,
    float* __restrict__ out, int E)
{
    const float C5 = -0.32f;          // -0.5 / 1.25^2
    const float C4 = -0.18f;          // -0.5 / (5/3)^2
    const float EK1  = 0.60653065971263342f;   // e^-0.5
    const float EK4  = 0.13533528323661270f;   // e^-2
    const float EK9  = 0.011108996538242306f;  // e^-4.5
    const float EK16 = 3.3546262790251185e-4f; // e^-8

    __shared__ __align__(16) unsigned char LDSB[4][4608];

    int tid = threadIdx.x;
    int wid = tid >> 6, lane = tid & 63;
    int e = blockIdx.x * 256 + wid * 64 + lane;
    int el = e < E ? e : (E - 1);   // clamped load index (no early return)

    const float4* lp = (const float4*)lig + 3 * (size_t)el;
    const float4* rp = (const float4*)rec + 3 * (size_t)el;
    float4 l0 = lp[0], l1 = lp[1], l2 = lp[2];
    float4 r0 = rp[0], r1 = rp[1], r2 = rp[2];

    float e1x = l0.w - r0.w, e1y = l1.x - r1.x, e1z = l1.y - r1.y;
    float e2x = l1.z - r1.z, e2y = l1.w - r1.w, e2z = l2.x - r2.x;
    float e3x = l2.y - r2.y, e3y = l2.z - r2.z, e3z = l2.w - r2.w;

    float q1 = fmaf(e1x, e1x, fmaf(e1y, e1y, e1z * e1z)) + 1e-12f;
    float q2 = fmaf(e2x, e2x, fmaf(e2y, e2y, e2z * e2z)) + 1e-12f;
    float q3 = fmaf(e3x, e3x, fmaf(e3y, e3y, e3z * e3z)) + 1e-12f;
    float ri1 = rsqrtf(q1), ri2 = rsqrtf(q2), ri3 = rsqrtf(q3);
    float d1 = q1 * ri1, d2 = q2 * ri2, d3 = q3 * ri3;
    float v1x = e1x * ri1, v1y = e1y * ri1, v1z = e1z * ri1;
    float v2x = e2x * ri2, v2y = e2y * ri2, v2z = e2z * ri2;
    float v3x = e3x * ri3, v3y = e3y * ri3, v3z = e3z * ri3;

    float s1[5], s3[5], s2[4];
    {
        float E0 = __expf(C5 * d1 * d1), r = __expf(0.8f * d1);
        float rr = r * r, u = E0 * r, v = E0 * rr;
        s1[0] = E0; s1[1] = u * EK1; s1[2] = v * EK4;
        s1[3] = v * r * EK9; s1[4] = v * rr * EK16;
    }
    {
        float E0 = __expf(C5 * d3 * d3), r = __expf(0.8f * d3);
        float rr = r * r, u = E0 * r, v = E0 * rr;
        s3[0] = E0; s3[1] = u * EK1; s3[2] = v * EK4;
        s3[3] = v * r * EK9; s3[4] = v * rr * EK16;
    }
    {
        float E0 = __expf(C4 * d2 * d2), r = __expf(0.6f * d2);
        float rr = r * r;
        s2[0] = E0; s2[1] = E0 * r * EK1; s2[2] = E0 * rr * EK4;
        s2[3] = E0 * rr * r * EK9;
    }

    float dot12 = fmaf(v1x, v2x, fmaf(v1y, v2y, v1z * v2z));  // raw
    float cr12x = v1y * v2z - v1z * v2y;                       // raw
    float cr12y = v1z * v2x - v1x * v2z;
    float cr12z = v1x * v2y - v1y * v2x;

    // ---- vector path (f32, proven) — run FIRST to minimize live state later
    float A[5], B[5];
#pragma unroll
    for (int k = 0; k < 5; k++) {
        float a = 0.f, b = 0.f;
#pragma unroll
        for (int i = 0; i < 5; i++) a = fmaf(s1[i], SVV[i * 5 + k], a);
#pragma unroll
        for (int j = 0; j < 4; j++) b = fmaf(s2[j], VSV[j * 5 + k], b);
        A[k] = a; B[k] = b;
    }
    float ov[5][3];
#pragma unroll
    for (int k = 0; k < 5; k++) {
        float w = VVV1[k];
        ov[k][0] = fmaf(A[k], v2x, fmaf(B[k], v1x, cr12x * w));
        ov[k][1] = fmaf(A[k], v2y, fmaf(B[k], v1y, cr12y * w));
        ov[k][2] = fmaf(A[k], v2z, fmaf(B[k], v1z, cr12z * w));
    }
    float dot2[5];
#pragma unroll
    for (int k = 0; k < 5; k++)
        dot2[k] = fmaf(ov[k][0], v3x, fmaf(ov[k][1], v3y, ov[k][2] * v3z)); // raw

    float accsV[9];
#pragma unroll
    for (int o = 0; o < 9; o++) accsV[o] = 0.f;
#pragma unroll
    for (int k = 0; k < 5; k++)
#pragma unroll
        for (int o = 0; o < 9; o++) accsV[o] = fmaf(dot2[k], VVO2[k * 9 + o], accsV[o]);

    float av0 = 0.f, av1 = 0.f, av2 = 0.f;
#pragma unroll
    for (int k = 0; k < 5; k++) {
        float c = 0.f;
#pragma unroll
        for (int j = 0; j < 5; j++) c = fmaf(s3[j], VSV2[k * 5 + j], c);
        float w = VVV2[k];
        float cx = ov[k][1] * v3z - ov[k][2] * v3y;  // raw cross
        float cy = ov[k][2] * v3x - ov[k][0] * v3z;
        float cz = ov[k][0] * v3y - ov[k][1] * v3x;
        av0 = fmaf(ov[k][0], c, fmaf(cx, w, av0));
        av1 = fmaf(ov[k][1], c, fmaf(cy, w, av1));
        av2 = fmaf(ov[k][2], c, fmaf(cz, w, av2));
    }
    // ov, A, B, cr12, v1, v2 dead from here

    // ---- f16 features
    _Float16 s1f[5], s2f[4], s3f[5], p12f[20], d12h;
#pragma unroll
    for (int i = 0; i < 5; i++) s1f[i] = (_Float16)s1[i];
#pragma unroll
    for (int j = 0; j < 4; j++) s2f[j] = (_Float16)s2[j];
#pragma unroll
    for (int i = 0; i < 5; i++) s3f[i] = (_Float16)s3[i];
#pragma unroll
    for (int i = 0; i < 5; i++)
#pragma unroll
        for (int j = 0; j < 4; j++) p12f[i * 4 + j] = s1f[i] * s2f[j];
    d12h = (_Float16)dot12;

    // ---- B fragments (per-lane coalesced, L2-resident): slice s, lane -> 4 dw
    f4v bf0, bf1, bf2, bf3;
    {
        const f4v* BFp = (const f4v*)BF;
        bf0 = BFp[0 * 64 + lane];
        bf1 = BFp[1 * 64 + lane];
        bf2 = BFp[2 * 64 + lane];
        bf3 = BFp[3 * 64 + lane];
    }

    char* fb = (char*)(&LDSB[wid][0]);
    int rowA = lane & 15, grp = lane >> 4;

    f4v c0 = {0.f,0.f,0.f,0.f}, c1 = c0, c2 = c0, c3 = c0;
#pragma unroll
    for (int r = 0; r < 4; r++) {
        // write this K-slice's 32 features (4 x b128)
#pragma unroll
        for (int g = 0; g < 4; g++) {
            h2 pr0 = { FEAT(r * 32 + g * 8 + 0), FEAT(r * 32 + g * 8 + 1) };
            h2 pr1 = { FEAT(r * 32 + g * 8 + 2), FEAT(r * 32 + g * 8 + 3) };
            h2 pr2 = { FEAT(r * 32 + g * 8 + 4), FEAT(r * 32 + g * 8 + 5) };
            h2 pr3 = { FEAT(r * 32 + g * 8 + 6), FEAT(r * 32 + g * 8 + 7) };
            f4v val = { __builtin_bit_cast(float, pr0), __builtin_bit_cast(float, pr1),
                        __builtin_bit_cast(float, pr2), __builtin_bit_cast(float, pr3) };
            *(f4v*)(fb + lane * 72 + g * 16) = val;
        }
        __syncthreads();
        // A fragments: row = rowA + 16m, k-group = grp
        f4v a0 = *(const f4v*)(fb + (rowA +  0) * 72 + grp * 16);
        f4v a1 = *(const f4v*)(fb + (rowA + 16) * 72 + grp * 16);
        f4v a2 = *(const f4v*)(fb + (rowA + 32) * 72 + grp * 16);
        f4v a3 = *(const f4v*)(fb + (rowA + 48) * 72 + grp * 16);
        f4v bfr = (r == 0) ? bf0 : (r == 1) ? bf1 : (r == 2) ? bf2 : bf3;
        c0 = __builtin_amdgcn_mfma_f32_16x16x32_f16(__builtin_bit_cast(h8, a0),
                 __builtin_bit_cast(h8, bfr), c0, 0, 0, 0);
        c1 = __builtin_amdgcn_mfma_f32_16x16x32_f16(__builtin_bit_cast(h8, a1),
                 __builtin_bit_cast(h8, bfr), c1, 0, 0, 0);
        c2 = __builtin_amdgcn_mfma_f32_16x16x32_f16(__builtin_bit_cast(h8, a2),
                 __builtin_bit_cast(h8, bfr), c2, 0, 0, 0);
        c3 = __builtin_amdgcn_mfma_f32_16x16x32_f16(__builtin_bit_cast(h8, a3),
                 __builtin_bit_cast(h8, bfr), c3, 0, 0, 0);
        __syncthreads();   // reads done before next round's overwrite
    }

    // ---- D redistribution through the same LDS slice ([64 rows][16 f32])
    // D layout (m89): col = lane&15, row(within tile) = grp*4 + reg
#pragma unroll
    for (int rr = 0; rr < 4; rr++) {
        *(float*)(fb + ( 0 + grp * 4 + rr) * 64 + rowA * 4) = c0[rr];
        *(float*)(fb + (16 + grp * 4 + rr) * 64 + rowA * 4) = c1[rr];
        *(float*)(fb + (32 + grp * 4 + rr) * 64 + rowA * 4) = c2[rr];
        *(float*)(fb + (48 + grp * 4 + rr) * 64 + rowA * 4) = c3[rr];
    }
    __syncthreads();
    f4v dA = *(const f4v*)(fb + lane * 64 + 0);
    f4v dB = *(const f4v*)(fb + lane * 64 + 16);
    f2v dC = *(const f2v*)(fb + lane * 64 + 32);

    float S = dC[1];
    av0 = fmaf(S, v3x, av0);
    av1 = fmaf(S, v3y, av1);
    av2 = fmaf(S, v3z, av2);

    if (e < E) {
        size_t E3 = (size_t)E * 3;
        size_t b = (size_t)e * 3;
        out[b + 0]          = dA[0] + accsV[0];   // s_rot
        out[b + 1]          = dA[1] + accsV[1];
        out[b + 2]          = dA[2] + accsV[2];
        out[E3 + b + 0]     = dA[3] + accsV[3];   // s_tr
        out[E3 + b + 1]     = dB[0] + accsV[4];
        out[E3 + b + 2]     = dB[1] + accsV[5];
        out[2 * E3 + b + 0] = dB[2] + accsV[6];   // t_rot
        out[2 * E3 + b + 1] = dB[3] + accsV[7];
        out[2 * E3 + b + 2] = dC[0] + accsV[8];
        out[3 * E3 + b + 0] = av0;                // t_tr
        out[3 * E3 + b + 1] = av1;
        out[3 * E3 + b + 2] = av2;
    }
}

extern "C" void kernel_launch(void* const* d_in, const int* in_sizes, int n_in,
                              void* d_out, int out_size, void* d_ws, size_t ws_size,
                              hipStream_t stream) {
    const float* lig    = (const float*)d_in[0];
    const float* rec    = (const float*)d_in[1];
    const float* W1_sso = (const float*)d_in[2];
    const float* W1_svv = (const float*)d_in[3];
    const float* W1_vsv = (const float*)d_in[4];
    const float* W1_vvv = (const float*)d_in[6];
    const float* W1_vvo = (const float*)d_in[5];
    const float* W2_sso = (const float*)d_in[7];
    const float* W2_svv = (const float*)d_in[8];
    const float* W2_vsv = (const float*)d_in[9];
    const float* W2_vvo = (const float*)d_in[10];
    const float* W2_vvv = (const float*)d_in[11];
    float* ws = (float*)d_ws;

    fds_precompose<<<1, 256, 0, stream>>>(W1_sso, W1_svv, W1_vsv, W1_vvo, W1_vvv,
                                          W2_sso, W2_svv, W2_vsv, W2_vvo, W2_vvv, ws);

    int E = in_sizes[0] / 12;  // N*3 / 12 = N/4 (divisible by 64)
    int blocks = (E + 255) / 256;
    fds_kernel<<<blocks, 256, 0, stream>>>(
        lig, rec,
        ws + WS_BF, ws + WS_SVV, ws + WS_VSV, ws + WS_VVV1,
        ws + WS_VSV2, ws + WS_VVV2, ws + WS_VVO2,
        (float*)d_out, E);
}

// Round 16
// 44.829 us; speedup vs baseline: 1.7219x; 1.7219x over previous
//
#include <hip/hip_runtime.h>
#include <math.h>

// R16 = R13 skeleton (rolled j3-loop, proven post-timing-stable, 42.5-45.8us)
// + fdot2-ification of the remaining f32 dot-shaped blocks via f16-packed
// precomposed weights: A/B builds (SVVH/VSVH), c[k] (VSV2H), dot2.VVO2 init
// (VVO2H); S-chain split into two 5-deep chains. j3 loop + W12H/WV/WSH/CS
// layout and ordering identical to R13.

typedef _Float16 h2 __attribute__((ext_vector_type(2)));

#define WS_W12H  0    // [5][10][9] f16x2 packs                  = 450
#define WS_WV    450  // [5][9] f32 *i21*i105*i3                 = 45
#define WS_WSH   495  // [10] f16x2 packs of WS pairs            = 10
#define WS_CS    505  // scalar f32                              = 1
#define WS_VVV1  506  // [5] f32 *i10*i2                         = 5
#define WS_VVV2  511  // [5] f32 *i2*i50                         = 5
#define WS_SVVH  516  // [5 k][3 p] h2: s1-pairs x W1_svv *i10   = 15
#define WS_VSVH  531  // [5 k][2 p] h2: s2-pairs x W1_vsv *i10   = 10
#define WS_VSV2H 541  // [5 k][3 p] h2: s3-pairs x W2_vsv *i50   = 15
#define WS_VVO2H 556  // [3 p][9 o] h2: dot2-pairs x W2_vvo *i3*i105 = 27
#define WS_TOT   583

__global__ __launch_bounds__(256) void fds_precompose(
    const float* __restrict__ W1_sso, const float* __restrict__ W1_svv,
    const float* __restrict__ W1_vsv, const float* __restrict__ W1_vvo,
    const float* __restrict__ W1_vvv, const float* __restrict__ W2_sso,
    const float* __restrict__ W2_svv, const float* __restrict__ W2_vsv,
    const float* __restrict__ W2_vvo, const float* __restrict__ W2_vvv,
    float* __restrict__ ws)
{
    const float I2 = 0.70710678118654752f, I3 = 0.57735026918962576f;
    const float I10 = 0.31622776601683794f, I21 = 0.21821789023599239f;
    const float I105 = 0.09759000729485332f, I50 = 0.14142135623730950f;
    int tid = threadIdx.x;
    // W12H[j3][q][o] = pack(f16(W12[2q,j3,o]), f16(W12[2q+1,j3,o]))
    for (int idx = tid; idx < 450; idx += 256) {
        int o = idx % 9, q = (idx / 9) % 10, j3 = idx / 90;
        float a0 = 0.f, a1 = 0.f;
        for (int k2 = 0; k2 < 20; k2++) {
            float w2 = W2_sso[(k2 * 5 + j3) * 9 + o];
            a0 = fmaf(W1_sso[(2 * q) * 20 + k2], w2, a0);
            a1 = fmaf(W1_sso[(2 * q + 1) * 20 + k2], w2, a1);
        }
        h2 p = { (_Float16)(a0 * (I21 * I105)), (_Float16)(a1 * (I21 * I105)) };
        ws[WS_W12H + idx] = __builtin_bit_cast(float, p);
    }
    for (int idx = tid; idx < 45; idx += 256) {
        int o = idx % 9, j3 = idx / 9;
        float acc = 0.f;
        for (int k2 = 0; k2 < 20; k2++)
            acc = fmaf(W1_vvo[k2], W2_sso[(k2 * 5 + j3) * 9 + o], acc);
        ws[WS_WV + idx] = acc * (I21 * I105 * I3);
    }
    for (int idx = tid; idx < 10; idx += 256) {
        float a0 = 0.f, a1 = 0.f;
        for (int k2 = 0; k2 < 20; k2++) {
            a0 = fmaf(W1_sso[(2 * idx) * 20 + k2], W2_svv[k2], a0);
            a1 = fmaf(W1_sso[(2 * idx + 1) * 20 + k2], W2_svv[k2], a1);
        }
        h2 p = { (_Float16)(a0 * (I21 * I50)), (_Float16)(a1 * (I21 * I50)) };
        ws[WS_WSH + idx] = __builtin_bit_cast(float, p);
    }
    if (tid == 0) {
        float acc = 0.f;
        for (int k2 = 0; k2 < 20; k2++) acc = fmaf(W1_vvo[k2], W2_svv[k2], acc);
        ws[WS_CS] = acc * (I21 * I50 * I3);
    }
    for (int idx = tid; idx < 5; idx += 256)  ws[WS_VVV1 + idx] = W1_vvv[idx] * (I10 * I2);
    for (int idx = tid; idx < 5; idx += 256)  ws[WS_VVV2 + idx] = W2_vvv[idx] * (I2 * I50);
    // SVVH[k][p]: pairs over i of W1_svv[i][k]*I10 (i=4 padded)
    for (int idx = tid; idx < 15; idx += 256) {
        int k = idx / 3, p = idx % 3;
        float f0 = W1_svv[(2 * p) * 5 + k] * I10;
        float f1 = (2 * p + 1 < 5) ? W1_svv[(2 * p + 1) * 5 + k] * I10 : 0.f;
        h2 h = { (_Float16)f0, (_Float16)f1 };
        ws[WS_SVVH + idx] = __builtin_bit_cast(float, h);
    }
    // VSVH[k][p]: pairs over j of W1_vsv[j][k]*I10 (j=0..3, exact)
    for (int idx = tid; idx < 10; idx += 256) {
        int k = idx / 2, p = idx % 2;
        h2 h = { (_Float16)(W1_vsv[(2 * p) * 5 + k] * I10),
                 (_Float16)(W1_vsv[(2 * p + 1) * 5 + k] * I10) };
        ws[WS_VSVH + idx] = __builtin_bit_cast(float, h);
    }
    // VSV2H[k][p]: pairs over j of W2_vsv[k][j]*I50 (j=4 padded)
    for (int idx = tid; idx < 15; idx += 256) {
        int k = idx / 3, p = idx % 3;
        float f0 = W2_vsv[k * 5 + 2 * p] * I50;
        float f1 = (2 * p + 1 < 5) ? W2_vsv[k * 5 + 2 * p + 1] * I50 : 0.f;
        h2 h = { (_Float16)f0, (_Float16)f1 };
        ws[WS_VSV2H + idx] = __builtin_bit_cast(float, h);
    }
    // VVO2H[p][o]: pairs over k of W2_vvo[k][o]*I3*I105 (k=4 padded)
    for (int idx = tid; idx < 27; idx += 256) {
        int o = idx % 9, p = idx / 9;
        float f0 = W2_vvo[(2 * p) * 9 + o] * (I3 * I105);
        float f1 = (2 * p + 1 < 5) ? W2_vvo[(2 * p + 1) * 9 + o] * (I3 * I105) : 0.f;
        h2 h = { (_Float16)f0, (_Float16)f1 };
        ws[WS_VVO2H + idx] = __builtin_bit_cast(float, h);
    }
}

__global__ __launch_bounds__(256) void fds_kernel(
    const float* __restrict__ lig, const float* __restrict__ rec,
    const float* __restrict__ W12Hf, const float* __restrict__ WV,
    const float* __restrict__ WSHf, const float* __restrict__ CSp,
    const float* __restrict__ VVV1, const float* __restrict__ VVV2,
    const float* __restrict__ SVVHf, const float* __restrict__ VSVHf,
    const float* __restrict__ VSV2Hf, const float* __restrict__ VVO2Hf,
    float* __restrict__ out, int E)
{
    const float C5 = -0.32f;          // -0.5 / 1.25^2
    const float C4 = -0.18f;          // -0.5 / (5/3)^2
    const float EK1  = 0.60653065971263342f;   // e^-0.5
    const float EK4  = 0.13533528323661270f;   // e^-2
    const float EK9  = 0.011108996538242306f;  // e^-4.5
    const float EK16 = 3.3546262790251185e-4f; // e^-8
    const float EM1  = 0.36787944117144233f;   // e^-1

    const h2* __restrict__ W12H  = (const h2*)W12Hf;
    const h2* __restrict__ WSH   = (const h2*)WSHf;
    const h2* __restrict__ SVVH  = (const h2*)SVVHf;
    const h2* __restrict__ VSVH  = (const h2*)VSVHf;
    const h2* __restrict__ VSV2H = (const h2*)VSV2Hf;
    const h2* __restrict__ VVO2H = (const h2*)VVO2Hf;

    int e = blockIdx.x * blockDim.x + threadIdx.x;
    if (e >= E) return;

    const float4* lp = (const float4*)lig + 3 * (size_t)e;
    const float4* rp = (const float4*)rec + 3 * (size_t)e;
    float4 l0 = lp[0], l1 = lp[1], l2 = lp[2];
    float4 r0 = rp[0], r1 = rp[1], r2 = rp[2];

    // row 4e+1 = floats 3..5, row 4e+2 = floats 6..8, row 4e+3 = floats 9..11
    float e1x = l0.w - r0.w, e1y = l1.x - r1.x, e1z = l1.y - r1.y;
    float e2x = l1.z - r1.z, e2y = l1.w - r1.w, e2z = l2.x - r2.x;
    float e3x = l2.y - r2.y, e3y = l2.z - r2.z, e3z = l2.w - r2.w;

    float q1 = fmaf(e1x, e1x, fmaf(e1y, e1y, e1z * e1z)) + 1e-12f;
    float q2 = fmaf(e2x, e2x, fmaf(e2y, e2y, e2z * e2z)) + 1e-12f;
    float q3 = fmaf(e3x, e3x, fmaf(e3y, e3y, e3z * e3z)) + 1e-12f;
    float ri1 = rsqrtf(q1), ri2 = rsqrtf(q2), ri3 = rsqrtf(q3);
    float d1 = q1 * ri1, d2 = q2 * ri2, d3 = q3 * ri3;
    float v1x = e1x * ri1, v1y = e1y * ri1, v1z = e1z * ri1;
    float v2x = e2x * ri2, v2y = e2y * ri2, v2z = e2z * ri2;
    float v3x = e3x * ri3, v3y = e3y * ri3, v3z = e3z * ri3;

    // smear: s[i] = exp(C*(d - h*i)^2) = E0 * r^i * K[i^2]
    float s1[5], s3[5], s2[4];
    float r3;
    {
        float E0 = __expf(C5 * d1 * d1), r = __expf(0.8f * d1);
        float rr = r * r, u = E0 * r, v = E0 * rr;
        s1[0] = E0; s1[1] = u * EK1; s1[2] = v * EK4;
        s1[3] = v * r * EK9; s1[4] = v * rr * EK16;
    }
    {
        float E0 = __expf(C5 * d3 * d3); r3 = __expf(0.8f * d3);
        float rr = r3 * r3, u = E0 * r3, v = E0 * rr;
        s3[0] = E0; s3[1] = u * EK1; s3[2] = v * EK4;
        s3[3] = v * r3 * EK9; s3[4] = v * rr * EK16;
    }
    {
        float E0 = __expf(C4 * d2 * d2), r = __expf(0.6f * d2);
        float rr = r * r;
        s2[0] = E0; s2[1] = E0 * r * EK1; s2[2] = E0 * rr * EK4;
        s2[3] = E0 * rr * r * EK9;
    }

    float dot12 = fmaf(v1x, v2x, fmaf(v1y, v2y, v1z * v2z));  // raw
    float cr12x = v1y * v2z - v1z * v2y;                       // raw
    float cr12y = v1z * v2x - v1x * v2z;
    float cr12z = v1x * v2y - v1y * v2x;

    // ---- f16 feature packs
    _Float16 s1f[5];
#pragma unroll
    for (int i = 0; i < 5; i++) s1f[i] = (_Float16)s1[i];
    h2 s1p0 = { s1f[0], s1f[1] }, s1p1 = { s1f[2], s1f[3] },
       s1p2 = { s1f[4], (_Float16)0.f };
    h2 s2p0 = { (_Float16)s2[0], (_Float16)s2[1] };
    h2 s2p1 = { (_Float16)s2[2], (_Float16)s2[3] };
    h2 p12h[10];
#pragma unroll
    for (int i = 0; i < 5; i++) {
        h2 s1b = { s1f[i], s1f[i] };
        p12h[i * 2 + 0] = s1b * s2p0;
        p12h[i * 2 + 1] = s1b * s2p1;
    }

    // S = p12 . WS + dot12 * cS  (two 5-deep chains)
    float S0 = dot12 * CSp[0], S1 = 0.f;
#pragma unroll
    for (int q = 0; q < 5; q++) S0 = __builtin_amdgcn_fdot2(p12h[q], WSH[q], S0, false);
#pragma unroll
    for (int q = 5; q < 10; q++) S1 = __builtin_amdgcn_fdot2(p12h[q], WSH[q], S1, false);
    float S = S0 + S1;

    // ---- j3-loop (NOT unrolled) — byte-identical structure to R13
    float accs[9];
#pragma unroll
    for (int o = 0; o < 9; o++) accs[o] = 0.f;
    {
        const h2* wj = W12H;
        const float* wv = WV;
        float s3c = s3[0];
        float uu = r3 * EK1;
#pragma clang loop unroll(disable)
        for (int j3 = 0; j3 < 5; ++j3) {
            float fv = dot12 * s3c;
#pragma unroll
            for (int o = 0; o < 9; o++) accs[o] = fmaf(fv, wv[o], accs[o]);
            _Float16 sh = (_Float16)s3c;
            h2 shb = (h2){ sh, sh };
#pragma unroll
            for (int q = 0; q < 10; q++) {
                h2 f = p12h[q] * shb;
#pragma unroll
                for (int o = 0; o < 9; o++)
                    accs[o] = __builtin_amdgcn_fdot2(f, wj[q * 9 + o], accs[o], false);
            }
            s3c *= uu; uu *= EM1;
            wj += 90; wv += 9;
        }
    }

    // ---- vector path (fdot2-ified builds), after the loop as in R13
    _Float16 s3f[5];
#pragma unroll
    for (int i = 0; i < 5; i++) s3f[i] = (_Float16)s3[i];
    h2 s3p0 = { s3f[0], s3f[1] }, s3p1 = { s3f[2], s3f[3] },
       s3p2 = { s3f[4], (_Float16)0.f };

    float A[5], B[5];
#pragma unroll
    for (int k = 0; k < 5; k++) {
        float a = __builtin_amdgcn_fdot2(s1p0, SVVH[3 * k + 0], 0.f, false);
        a = __builtin_amdgcn_fdot2(s1p1, SVVH[3 * k + 1], a, false);
        a = __builtin_amdgcn_fdot2(s1p2, SVVH[3 * k + 2], a, false);
        float b = __builtin_amdgcn_fdot2(s2p0, VSVH[2 * k + 0], 0.f, false);
        b = __builtin_amdgcn_fdot2(s2p1, VSVH[2 * k + 1], b, false);
        A[k] = a; B[k] = b;
    }
    float ov[5][3];
#pragma unroll
    for (int k = 0; k < 5; k++) {
        float w = VVV1[k];
        ov[k][0] = fmaf(A[k], v2x, fmaf(B[k], v1x, cr12x * w));
        ov[k][1] = fmaf(A[k], v2y, fmaf(B[k], v1y, cr12y * w));
        ov[k][2] = fmaf(A[k], v2z, fmaf(B[k], v1z, cr12z * w));
    }

    float dot2[5];
#pragma unroll
    for (int k = 0; k < 5; k++)
        dot2[k] = fmaf(ov[k][0], v3x, fmaf(ov[k][1], v3y, ov[k][2] * v3z)); // raw

    _Float16 d2f[5];
#pragma unroll
    for (int k = 0; k < 5; k++) d2f[k] = (_Float16)dot2[k];
    h2 d2p0 = { d2f[0], d2f[1] }, d2p1 = { d2f[2], d2f[3] },
       d2p2 = { d2f[4], (_Float16)0.f };
#pragma unroll
    for (int o = 0; o < 9; o++) {
        float t = __builtin_amdgcn_fdot2(d2p0, VVO2H[0 * 9 + o], accs[o], false);
        t = __builtin_amdgcn_fdot2(d2p1, VVO2H[1 * 9 + o], t, false);
        accs[o] = __builtin_amdgcn_fdot2(d2p2, VVO2H[2 * 9 + o], t, false);
    }

    float av0 = 0.f, av1 = 0.f, av2 = 0.f;
#pragma unroll
    for (int k = 0; k < 5; k++) {
        float c = __builtin_amdgcn_fdot2(s3p0, VSV2H[3 * k + 0], 0.f, false);
        c = __builtin_amdgcn_fdot2(s3p1, VSV2H[3 * k + 1], c, false);
        c = __builtin_amdgcn_fdot2(s3p2, VSV2H[3 * k + 2], c, false);
        float w = VVV2[k];
        float cx = ov[k][1] * v3z - ov[k][2] * v3y;  // raw cross
        float cy = ov[k][2] * v3x - ov[k][0] * v3z;
        float cz = ov[k][0] * v3y - ov[k][1] * v3x;
        av0 = fmaf(ov[k][0], c, fmaf(cx, w, av0));
        av1 = fmaf(ov[k][1], c, fmaf(cy, w, av1));
        av2 = fmaf(ov[k][2], c, fmaf(cz, w, av2));
    }
    av0 = fmaf(S, v3x, av0);
    av1 = fmaf(S, v3y, av1);
    av2 = fmaf(S, v3z, av2);

    size_t E3 = (size_t)E * 3;
    size_t b = (size_t)e * 3;
    out[b + 0]          = accs[0];   // s_rot
    out[b + 1]          = accs[1];
    out[b + 2]          = accs[2];
    out[E3 + b + 0]     = accs[3];   // s_tr
    out[E3 + b + 1]     = accs[4];
    out[E3 + b + 2]     = accs[5];
    out[2 * E3 + b + 0] = accs[6];   // t_rot
    out[2 * E3 + b + 1] = accs[7];
    out[2 * E3 + b + 2] = accs[8];
    out[3 * E3 + b + 0] = av0;       // t_tr
    out[3 * E3 + b + 1] = av1;
    out[3 * E3 + b + 2] = av2;
}

extern "C" void kernel_launch(void* const* d_in, const int* in_sizes, int n_in,
                              void* d_out, int out_size, void* d_ws, size_t ws_size,
                              hipStream_t stream) {
    const float* lig    = (const float*)d_in[0];
    const float* rec    = (const float*)d_in[1];
    const float* W1_sso = (const float*)d_in[2];
    const float* W1_svv = (const float*)d_in[3];
    const float* W1_vsv = (const float*)d_in[4];
    const float* W1_vvo = (const float*)d_in[5];
    const float* W1_vvv = (const float*)d_in[6];
    const float* W2_sso = (const float*)d_in[7];
    const float* W2_svv = (const float*)d_in[8];
    const float* W2_vsv = (const float*)d_in[9];
    const float* W2_vvo = (const float*)d_in[10];
    const float* W2_vvv = (const float*)d_in[11];
    float* ws = (float*)d_ws;

    fds_precompose<<<1, 256, 0, stream>>>(W1_sso, W1_svv, W1_vsv, W1_vvo, W1_vvv,
                                          W2_sso, W2_svv, W2_vsv, W2_vvo, W2_vvv, ws);

    int E = in_sizes[0] / 12;  // N*3 / 12 = N/4
    int blocks = (E + 255) / 256;
    fds_kernel<<<blocks, 256, 0, stream>>>(
        lig, rec,
        ws + WS_W12H, ws + WS_WV, ws + WS_WSH, ws + WS_CS,
        ws + WS_VVV1, ws + WS_VVV2,
        ws + WS_SVVH, ws + WS_VSVH, ws + WS_VSV2H, ws + WS_VVO2H,
        (float*)d_out, E);
}